// Round 4
// baseline (1281.436 us; speedup 1.0000x reference)
//
#include <hip/hip_runtime.h>
#include <hip/hip_bf16.h>
#include <math.h>
#include <stdio.h>

// BiMambaBlock: bidirectional Mamba forward.
// B=4, L=2048, D_MODEL=1024, D_INNER=2048, D_STATE=16, D_CONV=4, DT_RANK=64.
//
// R3 -> R4: ALL inputs and the output are FP32 (per reference dtypes). The
// R2/R3 NaN came from reading fp32 buffers as bf16 (mantissa bits decode to
// bf16 Inf/NaN ~1/256 of the time). GEMMs still use bf16 MFMA via explicit
// fp32->bf16 cast kernels for operands; accumulation and scan math are fp32;
// d_out is fp32. Sync LDS staging kept (one variable per round).
//
// Per direction (sequential, buffers reused; ws = 189.1 MB, overlaps:
// xA lives in dt region, in_w-bf16 in xc region, ow-bf16 in dead dt region):
//   cast x(/flip) + weights -> GEMM in_proj -> conv+silu -> GEMM x_proj ->
//   split B/C -> GEMM dt_proj(+softplus) -> chunked scan (A/B/C) -> gate ->
//   cast ow -> GEMM out (dir0: fp32 acc; dir1: add + time-flip + store fp32).
// Scan chunking: prod exp(dt*A) telescopes = exp2(A*log2e * sum dt);
// 16 chunks of 128 steps -> parallel local scans + tiny chain + correction.

using u16 = unsigned short;
using u32 = unsigned int;

typedef __bf16 bf16x8 __attribute__((ext_vector_type(8)));
typedef float  f32x4  __attribute__((ext_vector_type(4)));
typedef u32    u32x4  __attribute__((ext_vector_type(4)));
typedef u16    u16x4  __attribute__((ext_vector_type(4)));

#define DEVINL __device__ __forceinline__

DEVINL float b2f(u16 u) { union { u32 i; float f; } v; v.i = ((u32)u) << 16; return v.f; }
DEVINL u16 f2b(float f) {
  union { float f; u32 i; } v; v.f = f;
  u32 i = v.i;
  return (u16)((i + 0x7FFFu + ((i >> 16) & 1u)) >> 16);  // RNE; inputs are tame (no NaN)
}

// ---------------------------------------------------------------------------
// GEMM: C[m,n] = sum_k A[m,k] * B[n,k]   (both K-major, bf16 in, fp32 acc)
// 128x128 tile, BK=64, 256 threads (4 waves, each 64x64 = 4x4 mfma 16x16x32).
// MODE 0: store bf16       MODE 1: softplus(acc + bias[n]) -> bf16
// MODE 2: store fp32       MODE 3: fp32 store to out2 at row m^2047, += addsrc
// ---------------------------------------------------------------------------
template <int MODE>
__global__ __launch_bounds__(256) void k_gemm(
    const u16* __restrict__ A, int lda,
    const u16* __restrict__ Bw, int ldb,
    void* __restrict__ Cout, int ldc, int K,
    const float* __restrict__ bias,
    const float* __restrict__ addsrc, float* __restrict__ out2)
{
  __shared__ __align__(16) u16 As[128 * 64];
  __shared__ __align__(16) u16 Bs[128 * 64];

  const int tid  = threadIdx.x;
  const int lane = tid & 63;
  const int wid  = tid >> 6;

  const long long mBase = (long long)blockIdx.x * 128;
  const long long nBase = (long long)blockIdx.y * 128;

  f32x4 acc[4][4];
#pragma unroll
  for (int i = 0; i < 4; ++i)
#pragma unroll
    for (int j = 0; j < 4; ++j) acc[i][j] = (f32x4){0.f, 0.f, 0.f, 0.f};

  const int wm = (wid & 1) * 64;
  const int wn = (wid >> 1) * 64;
  const int lrow = lane & 15;
  const int lk   = (lane >> 4) * 8;
  const int sr = tid >> 3;         // staging row within 32-row group [0,32)
  const int sc = (tid & 7) * 8;    // staging col (8 bf16 = 16 B)

  for (int k0 = 0; k0 < K; k0 += 64) {
    // --- synchronous staging: each thread owns 4 distinct 16B LDS slots ---
#pragma unroll
    for (int i = 0; i < 4; ++i) {
      const int r = i * 32 + sr;
      const u32x4 va = *(const u32x4*)(A  + (mBase + r) * (long long)lda + (k0 + sc));
      const u32x4 vb = *(const u32x4*)(Bw + (nBase + r) * (long long)ldb + (k0 + sc));
      *(u32x4*)&As[r * 64 + sc] = va;
      *(u32x4*)&Bs[r * 64 + sc] = vb;
    }
    __syncthreads();
#pragma unroll
    for (int kk = 0; kk < 64; kk += 32) {
      bf16x8 af[4], bfr[4];
#pragma unroll
      for (int f = 0; f < 4; ++f) {
        af[f]  = *(const bf16x8*)&As[(wm + f * 16 + lrow) * 64 + kk + lk];
        bfr[f] = *(const bf16x8*)&Bs[(wn + f * 16 + lrow) * 64 + kk + lk];
      }
#pragma unroll
      for (int fm = 0; fm < 4; ++fm)
#pragma unroll
        for (int fn = 0; fn < 4; ++fn)
          acc[fm][fn] = __builtin_amdgcn_mfma_f32_16x16x32_bf16(af[fm], bfr[fn], acc[fm][fn], 0, 0, 0);
    }
    __syncthreads();
  }

  // epilogue: D lane mapping col = lane&15, row = (lane>>4)*4 + reg  [m89]
  const int rowq = (lane >> 4) * 4;
  const int coln = lane & 15;
#pragma unroll
  for (int fm = 0; fm < 4; ++fm) {
#pragma unroll
    for (int fn = 0; fn < 4; ++fn) {
#pragma unroll
      for (int r = 0; r < 4; ++r) {
        const long long m = mBase + wm + fm * 16 + rowq + r;
        const long long n = nBase + wn + fn * 16 + coln;
        const float v = acc[fm][fn][r];
        if constexpr (MODE == 0) {
          ((u16*)Cout)[m * ldc + n] = f2b(v);
        } else if constexpr (MODE == 1) {
          const float xv = v + bias[(int)n];
          const float sp = (xv > 20.f) ? xv : log1pf(expf(xv));
          ((u16*)Cout)[m * ldc + n] = f2b(sp);
        } else if constexpr (MODE == 2) {
          ((float*)Cout)[m * ldc + n] = v;
        } else {
          const long long mf = m ^ 2047;  // time flip within batch (L=2048)
          out2[mf * ldc + n] = v + addsrc[mf * ldc + n];
        }
      }
    }
  }
}

// ---------------------------------------------------------------------------
// cast / prep kernels (inputs fp32; weight pointers pre-offset per dir)
// ---------------------------------------------------------------------------
__global__ __launch_bounds__(256) void k_castw(const float* __restrict__ src,
                                               u16* __restrict__ dst) {
  const int i = blockIdx.x * 256 + threadIdx.x;  // one f32x4 chunk each
  const f32x4 v = ((const f32x4*)src)[i];
  u16x4 o = {f2b(v[0]), f2b(v[1]), f2b(v[2]), f2b(v[3])};
  ((u16x4*)dst)[i] = o;
}

// x (fp32 [4][2048][1024]) -> bf16, optional time flip per batch
__global__ __launch_bounds__(256) void k_cast_x(const float* __restrict__ x,
                                                u16* __restrict__ xA, int flip) {
  const int idx = blockIdx.x * 256 + threadIdx.x;  // [0, 4*2048*256)
  const int c = idx & 255;                         // f32x4 chunk within row
  const int l = (idx >> 8) & 2047;
  const int b = idx >> 19;
  const int ls = flip ? (2047 - l) : l;
  const f32x4 v = ((const f32x4*)x)[(long long)(b * 2048 + ls) * 256 + c];
  u16x4 o = {f2b(v[0]), f2b(v[1]), f2b(v[2]), f2b(v[3])};
  ((u16x4*)xA)[(long long)(b * 2048 + l) * 256 + c] = o;
}

__global__ __launch_bounds__(256) void k_prep_xw(const float* __restrict__ xpw,
                                                 u16* __restrict__ xw_pad) {
  const int idx = blockIdx.x * 256 + threadIdx.x;  // [0, 128*2048)
  const int c = idx & 2047;
  const int r = idx >> 11;
  xw_pad[idx] = (r < 96) ? f2b(xpw[r * 2048 + c]) : (u16)0;
}

__global__ __launch_bounds__(256) void k_prep_a2(const float* __restrict__ alog,
                                                 float* __restrict__ A2) {
  const int idx = blockIdx.x * 256 + threadIdx.x;  // [0, 2048*16)
  A2[idx] = -expf(alog[idx]) * 1.4426950408889634f;  // A * log2(e)
}

__global__ __launch_bounds__(256) void k_prep_bc(const u16* __restrict__ proj,
                                                 float* __restrict__ Bf,
                                                 float* __restrict__ Cf) {
  const int idx = blockIdx.x * 256 + threadIdx.x;  // [0, 8192*32)
  const int c = idx & 31;
  const long long gr = idx >> 5;
  const float v = b2f(proj[gr * 128 + 64 + c]);
  if (c < 16) Bf[gr * 16 + c] = v;
  else        Cf[gr * 16 + (c - 16)] = v;
}

// ---------------------------------------------------------------------------
// depthwise causal conv (k=4) + bias + silu.  xi lives in xz cols [0,2048).
// ---------------------------------------------------------------------------
__global__ __launch_bounds__(256) void k_conv(const u16* __restrict__ xz,
                                              const float* __restrict__ cw,
                                              const float* __restrict__ cb,
                                              u16* __restrict__ xc) {
  const int idx = blockIdx.x * 256 + threadIdx.x;  // [0, 8192*256)
  const int d8  = idx & 255;
  const int gr  = idx >> 8;
  const int t   = gr & 2047;
  const int d0  = d8 * 8;

  float acc[8];
#pragma unroll
  for (int j = 0; j < 8; ++j) acc[j] = cb[d0 + j];

#pragma unroll
  for (int k = 0; k < 4; ++k) {
    const int tt = t - 3 + k;
    if (tt < 0) continue;
    const u32x4 v = *(const u32x4*)(xz + (long long)(gr + k - 3) * 4096 + d0);
    const u16* pv = (const u16*)&v;
#pragma unroll
    for (int j = 0; j < 8; ++j)
      acc[j] = fmaf(cw[(d0 + j) * 4 + k], b2f(pv[j]), acc[j]);
  }
  u16 o[8];
#pragma unroll
  for (int j = 0; j < 8; ++j) {
    const float a = acc[j];
    o[j] = f2b(a / (1.f + expf(-a)));  // silu
  }
  *(u32x4*)(xc + (long long)gr * 2048 + d0) = *(const u32x4*)o;
}

// ---------------------------------------------------------------------------
// scan phase A: per-chunk local scan (h starts at 0). Writes y_local into the
// xi region of xz, plus chunk summaries h_loc[b][c][s][d] and sumdt[b][c][d].
// grid: 4(b) * 16(chunk) * 8(dchunk) = 512 blocks
// ---------------------------------------------------------------------------
__global__ __launch_bounds__(256) void k_scanA(
    const u16* __restrict__ dt, const u16* __restrict__ xc,
    const float* __restrict__ Bf, const float* __restrict__ Cf,
    const float* __restrict__ A2, u16* __restrict__ yz,
    float* __restrict__ h_loc, float* __restrict__ sumdt)
{
  const int tid = threadIdx.x;
  const int bx  = blockIdx.x;
  const int d     = (bx & 7) * 256 + tid;
  const int chunk = (bx >> 3) & 15;
  const int b     = bx >> 7;

  float a2[16];
#pragma unroll
  for (int s = 0; s < 16; ++s) a2[s] = A2[d * 16 + s];

  float h[16];
#pragma unroll
  for (int s = 0; s < 16; ++s) h[s] = 0.f;
  float sdt = 0.f;

  const long long rowBase = (long long)b * 2048 + chunk * 128;
  for (int t0 = 0; t0 < 128; ++t0) {
    const long long gr = rowBase + t0;
    const float dtv = b2f(dt[gr * 2048 + d]);
    const float xcv = b2f(xc[gr * 2048 + d]);
    sdt += dtv;
    const float dtx = dtv * xcv;
    float Bv[16], Cv[16];
    *(f32x4*)&Bv[0]  = *(const f32x4*)(Bf + gr * 16);
    *(f32x4*)&Bv[4]  = *(const f32x4*)(Bf + gr * 16 + 4);
    *(f32x4*)&Bv[8]  = *(const f32x4*)(Bf + gr * 16 + 8);
    *(f32x4*)&Bv[12] = *(const f32x4*)(Bf + gr * 16 + 12);
    *(f32x4*)&Cv[0]  = *(const f32x4*)(Cf + gr * 16);
    *(f32x4*)&Cv[4]  = *(const f32x4*)(Cf + gr * 16 + 4);
    *(f32x4*)&Cv[8]  = *(const f32x4*)(Cf + gr * 16 + 8);
    *(f32x4*)&Cv[12] = *(const f32x4*)(Cf + gr * 16 + 12);
    float y = 0.f;
#pragma unroll
    for (int s = 0; s < 16; ++s) {
      const float dA = __builtin_amdgcn_exp2f(a2[s] * dtv);
      h[s] = fmaf(h[s], dA, dtx * Bv[s]);
      y = fmaf(h[s], Cv[s], y);
    }
    yz[gr * 4096 + d] = f2b(y);
  }
  const long long cbi = (long long)b * 16 + chunk;
#pragma unroll
  for (int s = 0; s < 16; ++s) h_loc[(cbi * 16 + s) * 2048 + d] = h[s];
  sumdt[cbi * 2048 + d] = sdt;
}

// phase B: chain chunk states. h_in[c] = state entering chunk c. grid: 4*8=32
__global__ __launch_bounds__(256) void k_scanB(
    const float* __restrict__ A2, const float* __restrict__ h_loc,
    const float* __restrict__ sumdt, float* __restrict__ h_in)
{
  const int tid = threadIdx.x;
  const int bx  = blockIdx.x;
  const int d   = (bx & 7) * 256 + tid;
  const int b   = bx >> 3;

  float a2[16];
#pragma unroll
  for (int s = 0; s < 16; ++s) a2[s] = A2[d * 16 + s];
  float h[16];
#pragma unroll
  for (int s = 0; s < 16; ++s) h[s] = 0.f;

  const long long base = (long long)b * 16;
  for (int c = 0; c < 16; ++c) {
    const long long cbi = base + c;
#pragma unroll
    for (int s = 0; s < 16; ++s) h_in[(cbi * 16 + s) * 2048 + d] = h[s];
    const float sd = sumdt[cbi * 2048 + d];
#pragma unroll
    for (int s = 0; s < 16; ++s) {
      const float P = __builtin_amdgcn_exp2f(a2[s] * sd);
      h[s] = fmaf(h[s], P, h_loc[(cbi * 16 + s) * 2048 + d]);
    }
  }
}

// phase C: y_t += C_t . (exp2(a2 * cumdt_t) ⊙ h_in). chunks 1..15. grid 480
__global__ __launch_bounds__(256) void k_scanC(
    const u16* __restrict__ dt, const float* __restrict__ Cf,
    const float* __restrict__ A2, const float* __restrict__ h_in,
    u16* __restrict__ yz)
{
  const int tid = threadIdx.x;
  const int bx  = blockIdx.x;
  const int d   = (bx & 7) * 256 + tid;
  int r = bx >> 3;
  const int chunk = (r % 15) + 1;
  const int b = r / 15;

  float a2[16];
#pragma unroll
  for (int s = 0; s < 16; ++s) a2[s] = A2[d * 16 + s];
  const long long cbi = (long long)b * 16 + chunk;
  float hv[16];
#pragma unroll
  for (int s = 0; s < 16; ++s) hv[s] = h_in[(cbi * 16 + s) * 2048 + d];

  float cum = 0.f;
  const long long rowBase = (long long)b * 2048 + chunk * 128;
  for (int t0 = 0; t0 < 128; ++t0) {
    const long long gr = rowBase + t0;
    cum += b2f(dt[gr * 2048 + d]);
    float Cv[16];
    *(f32x4*)&Cv[0]  = *(const f32x4*)(Cf + gr * 16);
    *(f32x4*)&Cv[4]  = *(const f32x4*)(Cf + gr * 16 + 4);
    *(f32x4*)&Cv[8]  = *(const f32x4*)(Cf + gr * 16 + 8);
    *(f32x4*)&Cv[12] = *(const f32x4*)(Cf + gr * 16 + 12);
    float g = 0.f;
#pragma unroll
    for (int s = 0; s < 16; ++s) {
      const float w = __builtin_amdgcn_exp2f(a2[s] * cum);
      g = fmaf(w * hv[s], Cv[s], g);
    }
    u16* yp = &yz[gr * 4096 + d];
    *yp = f2b(b2f(*yp) + g);
  }
}

// gate: y = (y + xc*Dp) * silu(z), in place in xz cols [0,2048). grid 8192
__global__ __launch_bounds__(256) void k_gate(u16* __restrict__ xz,
                                              const u16* __restrict__ xc,
                                              const float* __restrict__ Dp) {
  const int idx = blockIdx.x * 256 + threadIdx.x;  // [0, 8192*256)
  const int d8  = idx & 255;
  const int gr  = idx >> 8;
  const int d0  = d8 * 8;

  u16* yp = xz + (long long)gr * 4096 + d0;
  const u32x4 yv = *(const u32x4*)yp;
  const u32x4 zv = *(const u32x4*)(xz + (long long)gr * 4096 + 2048 + d0);
  const u32x4 xv = *(const u32x4*)(xc + (long long)gr * 2048 + d0);
  const u16* ya = (const u16*)&yv;
  const u16* za = (const u16*)&zv;
  const u16* xa = (const u16*)&xv;
  u16 o[8];
#pragma unroll
  for (int j = 0; j < 8; ++j) {
    const float y = b2f(ya[j]) + b2f(xa[j]) * Dp[d0 + j];
    const float z = b2f(za[j]);
    o[j] = f2b(y * (z / (1.f + expf(-z))));
  }
  *(u32x4*)yp = *(const u32x4*)o;
}

// ---------------------------------------------------------------------------
extern "C" void kernel_launch(void* const* d_in, const int* in_sizes, int n_in,
                              void* d_out, int out_size, void* d_ws, size_t ws_size,
                              hipStream_t stream) {
  const float* x    = (const float*)d_in[0];
  const float* inw  = (const float*)d_in[1];
  const float* cw   = (const float*)d_in[2];
  const float* cb   = (const float*)d_in[3];
  const float* xpw  = (const float*)d_in[4];
  const float* dtw  = (const float*)d_in[5];
  const float* dtb  = (const float*)d_in[6];
  const float* alog = (const float*)d_in[7];
  const float* Dp   = (const float*)d_in[8];
  const float* ow   = (const float*)d_in[9];
  float* out = (float*)d_out;

  // workspace layout (bytes) — per-direction buffers reused across dir 0/1.
  char* ws = (char*)d_ws;
  float* outacc = (float*)(ws + 0);          //  33,554,432  [8192][1024] fp32
  u16*   xz_d   = (u16*)(ws + 33554432);     //  67,108,864  [8192][4096] xi|z -> y|z
  u16*   xc_d   = (u16*)(ws + 100663296);    //  33,554,432  [8192][2048]
  u16*   inwB   = (u16*)(ws + 100663296);    //   8,388,608  [4096][1024] (dead before conv)
  u16*   dt_d   = (u16*)(ws + 134217728);    //  33,554,432  [8192][2048]
  u16*   xA     = (u16*)(ws + 134217728);    //  16,777,216  [8192][1024] (dead before dt_proj)
  u16*   owB    = (u16*)(ws + 134217728);    //   4,194,304  [1024][2048] (after scanC/gate)
  u16*   proj_d = (u16*)(ws + 167772160);    //   2,097,152  [8192][128]
  u16*   xw_pad = (u16*)(ws + 169869312);    //     524,288  [128][2048]
  float* A2     = (float*)(ws + 170393600);  //     131,072  [2048][16]
  float* Bf     = (float*)(ws + 170524672);  //     524,288  [8192][16]
  float* Cf     = (float*)(ws + 171048960);  //     524,288
  float* h_loc  = (float*)(ws + 171573248);  //   8,388,608  [64][16][2048]
  float* h_in   = (float*)(ws + 179961856);  //   8,388,608
  float* sumdt  = (float*)(ws + 188350464);  //     524,288  [64][2048]
  u16*   dtwB   = (u16*)(ws + 188874752);    //     262,144  [2048][64]
  const size_t NEED = 189136896;

  (void)in_sizes; (void)n_in; (void)out_size;
  if (ws_size < NEED) {  // deterministic guard: leaves d_out zeroed -> clean fail
    fprintf(stderr, "[BiMamba] ws_size=%zu < needed %zu — aborting launch\n", ws_size, NEED);
    return;
  }

  for (int dir = 0; dir < 2; ++dir) {
    const float* inw_d = inw + (long long)dir * 4096 * 1024;
    const float* cw_d  = cw  + dir * 2048 * 4;
    const float* cb_d  = cb  + dir * 2048;
    const float* xpw_d = xpw + dir * 96 * 2048;
    const float* dtw_d = dtw + dir * 2048 * 64;
    const float* dtb_d = dtb + dir * 2048;
    const float* al_d  = alog + dir * 2048 * 16;
    const float* Dp_d  = Dp  + dir * 2048;
    const float* ow_d  = ow  + (long long)dir * 1024 * 2048;

    // casts & prep (xA in dt region; inwB in xc region — both dead later)
    k_cast_x<<<8192, 256, 0, stream>>>(x, xA, dir);
    k_castw<<<4096, 256, 0, stream>>>(inw_d, inwB);     // 4096*1024 /4 /256
    k_prep_xw<<<1024, 256, 0, stream>>>(xpw_d, xw_pad);
    k_castw<<<128, 256, 0, stream>>>(dtw_d, dtwB);      // 2048*64 /4 /256
    k_prep_a2<<<128, 256, 0, stream>>>(al_d, A2);

    // in_proj: xz = xA[8192,1024] x inwB[4096,1024]^T
    k_gemm<0><<<dim3(64, 32), 256, 0, stream>>>(
        xA, 1024, inwB, 1024, xz_d, 4096, 1024, nullptr, nullptr, nullptr);

    k_conv<<<8192, 256, 0, stream>>>(xz_d, cw_d, cb_d, xc_d);

    // x_proj: proj = xc[8192,2048] x xw_pad[128,2048]^T
    k_gemm<0><<<dim3(64, 1), 256, 0, stream>>>(
        xc_d, 2048, xw_pad, 2048, proj_d, 128, 2048, nullptr, nullptr, nullptr);

    k_prep_bc<<<1024, 256, 0, stream>>>(proj_d, Bf, Cf);

    // dt_proj: dt = softplus(proj[:, :64] x dtwB[2048,64]^T + dtb)
    k_gemm<1><<<dim3(64, 16), 256, 0, stream>>>(
        proj_d, 128, dtwB, 64, dt_d, 2048, 64, dtb_d, nullptr, nullptr);

    k_scanA<<<512, 256, 0, stream>>>(dt_d, xc_d, Bf, Cf, A2, xz_d, h_loc, sumdt);
    k_scanB<<<32, 256, 0, stream>>>(A2, h_loc, sumdt, h_in);
    k_scanC<<<480, 256, 0, stream>>>(dt_d, Cf, A2, h_in, xz_d);

    k_gate<<<8192, 256, 0, stream>>>(xz_d, xc_d, Dp_d);

    // out_proj weights -> bf16 (into dead dt region; dt unused after scanC)
    k_castw<<<2048, 256, 0, stream>>>(ow_d, owB);       // 1024*2048 /4 /256

    if (dir == 0) {
      // out_proj dir0 -> fp32 accumulator
      k_gemm<2><<<dim3(64, 8), 256, 0, stream>>>(
          xz_d, 4096, owB, 2048, outacc, 1024, 2048, nullptr, nullptr, nullptr);
    } else {
      // out_proj dir1: time-flip rows, add dir0, store fp32 to d_out
      k_gemm<3><<<dim3(64, 8), 256, 0, stream>>>(
          xz_d, 4096, owB, 2048, nullptr, 1024, 2048, nullptr, outacc, out);
    }
  }
}

// Round 5
// 1244.286 us; speedup vs baseline: 1.0299x; 1.0299x over previous
//
#include <hip/hip_runtime.h>
#include <hip/hip_bf16.h>
#include <math.h>
#include <stdio.h>

// BiMambaBlock: bidirectional Mamba forward.
// B=4, L=2048, D_MODEL=1024, D_INNER=2048, D_STATE=16, D_CONV=4, DT_RANK=64.
// Inputs/output fp32; GEMMs run bf16 MFMA (fp32 acc) via cast kernels.
//
// R4 -> R5: restore width-16 global_load_lds async staging in k_gemm (the
// m93->m97 1.69x step). R4's sync staging measured 547 TF effective on
// in_proj (MfmaUtil 22.6%) == the documented no-async level. The async LDS
// granule mapping r*8+c is byte-identical to the sync layout, so this is a
// pure staging-engine swap; compute/epilogue untouched.
//
// Per direction (sequential, buffers reused; ws = 189.1 MB):
//   cast x(/flip) + weights -> GEMM in_proj -> conv+silu -> GEMM x_proj ->
//   split B/C -> GEMM dt_proj(+softplus) -> chunked scan (A/B/C) -> gate ->
//   cast ow -> GEMM out (dir0: fp32 acc; dir1: add + time-flip + store fp32).
// Scan chunking: prod exp(dt*A) telescopes = exp2(A*log2e * sum dt);
// 16 chunks of 128 steps -> parallel local scans + tiny chain + correction.

using u16 = unsigned short;
using u32 = unsigned int;

typedef __bf16 bf16x8 __attribute__((ext_vector_type(8)));
typedef float  f32x4  __attribute__((ext_vector_type(4)));
typedef u32    u32x4  __attribute__((ext_vector_type(4)));
typedef u16    u16x4  __attribute__((ext_vector_type(4)));

#define DEVINL __device__ __forceinline__

DEVINL float b2f(u16 u) { union { u32 i; float f; } v; v.i = ((u32)u) << 16; return v.f; }
DEVINL u16 f2b(float f) {
  union { float f; u32 i; } v; v.f = f;
  u32 i = v.i;
  return (u16)((i + 0x7FFFu + ((i >> 16) & 1u)) >> 16);  // RNE; inputs are tame (no NaN)
}

DEVINL void gl_lds16(const u16* g, u16* l) {
  __builtin_amdgcn_global_load_lds(
      (__attribute__((address_space(1))) void*)const_cast<u16*>(g),
      (__attribute__((address_space(3))) void*)l, 16, 0, 0);
}

// ---------------------------------------------------------------------------
// GEMM: C[m,n] = sum_k A[m,k] * B[n,k]   (both K-major, bf16 in, fp32 acc)
// 128x128 tile, BK=64, 256 threads (4 waves, each 64x64 = 4x4 mfma 16x16x32).
// MODE 0: store bf16       MODE 1: softplus(acc + bias[n]) -> bf16
// MODE 2: store fp32       MODE 3: fp32 store to out2 at row m^2047, += addsrc
// ---------------------------------------------------------------------------
template <int MODE>
__global__ __launch_bounds__(256) void k_gemm(
    const u16* __restrict__ A, int lda,
    const u16* __restrict__ Bw, int ldb,
    void* __restrict__ Cout, int ldc, int K,
    const float* __restrict__ bias,
    const float* __restrict__ addsrc, float* __restrict__ out2)
{
  __shared__ __align__(16) u16 As[128 * 64];
  __shared__ __align__(16) u16 Bs[128 * 64];

  const int tid  = threadIdx.x;
  const int lane = tid & 63;
  const int wid  = tid >> 6;

  const long long mBase = (long long)blockIdx.x * 128;
  const long long nBase = (long long)blockIdx.y * 128;

  f32x4 acc[4][4];
#pragma unroll
  for (int i = 0; i < 4; ++i)
#pragma unroll
    for (int j = 0; j < 4; ++j) acc[i][j] = (f32x4){0.f, 0.f, 0.f, 0.f};

  const int wm = (wid & 1) * 64;
  const int wn = (wid >> 1) * 64;
  const int lrow = lane & 15;
  const int lk   = (lane >> 4) * 8;
  const int sr = tid >> 3;         // staging row within 32-row group [0,32)
  const int sc = (tid & 7) * 8;    // staging col (8 bf16 = 16 B)

  for (int k0 = 0; k0 < K; k0 += 64) {
    // async staging: wave-uniform LDS base + HW lane*16B. Granule index
    // (i*32 + wid*8 + (lane>>3))*8 + (lane&7) == r*8 + c -> row-major [r][c].
#pragma unroll
    for (int i = 0; i < 4; ++i) {
      const int r = i * 32 + sr;
      u16* la = &As[(i * 256 + wid * 64) * 8];
      u16* lb = &Bs[(i * 256 + wid * 64) * 8];
      gl_lds16(A  + (mBase + r) * (long long)lda + (k0 + sc), la);
      gl_lds16(Bw + (nBase + r) * (long long)ldb + (k0 + sc), lb);
    }
    __syncthreads();  // drains vmcnt before s_barrier (compiler-inserted)
#pragma unroll
    for (int kk = 0; kk < 64; kk += 32) {
      bf16x8 af[4], bfr[4];
#pragma unroll
      for (int f = 0; f < 4; ++f) {
        af[f]  = *(const bf16x8*)&As[(wm + f * 16 + lrow) * 64 + kk + lk];
        bfr[f] = *(const bf16x8*)&Bs[(wn + f * 16 + lrow) * 64 + kk + lk];
      }
#pragma unroll
      for (int fm = 0; fm < 4; ++fm)
#pragma unroll
        for (int fn = 0; fn < 4; ++fn)
          acc[fm][fn] = __builtin_amdgcn_mfma_f32_16x16x32_bf16(af[fm], bfr[fn], acc[fm][fn], 0, 0, 0);
    }
    __syncthreads();
  }

  // epilogue: D lane mapping col = lane&15, row = (lane>>4)*4 + reg  [m89]
  const int rowq = (lane >> 4) * 4;
  const int coln = lane & 15;
#pragma unroll
  for (int fm = 0; fm < 4; ++fm) {
#pragma unroll
    for (int fn = 0; fn < 4; ++fn) {
#pragma unroll
      for (int r = 0; r < 4; ++r) {
        const long long m = mBase + wm + fm * 16 + rowq + r;
        const long long n = nBase + wn + fn * 16 + coln;
        const float v = acc[fm][fn][r];
        if constexpr (MODE == 0) {
          ((u16*)Cout)[m * ldc + n] = f2b(v);
        } else if constexpr (MODE == 1) {
          const float xv = v + bias[(int)n];
          const float sp = (xv > 20.f) ? xv : log1pf(expf(xv));
          ((u16*)Cout)[m * ldc + n] = f2b(sp);
        } else if constexpr (MODE == 2) {
          ((float*)Cout)[m * ldc + n] = v;
        } else {
          const long long mf = m ^ 2047;  // time flip within batch (L=2048)
          out2[mf * ldc + n] = v + addsrc[mf * ldc + n];
        }
      }
    }
  }
}

// ---------------------------------------------------------------------------
// cast / prep kernels (inputs fp32; weight pointers pre-offset per dir)
// ---------------------------------------------------------------------------
__global__ __launch_bounds__(256) void k_castw(const float* __restrict__ src,
                                               u16* __restrict__ dst) {
  const int i = blockIdx.x * 256 + threadIdx.x;  // one f32x4 chunk each
  const f32x4 v = ((const f32x4*)src)[i];
  u16x4 o = {f2b(v[0]), f2b(v[1]), f2b(v[2]), f2b(v[3])};
  ((u16x4*)dst)[i] = o;
}

// x (fp32 [4][2048][1024]) -> bf16, optional time flip per batch
__global__ __launch_bounds__(256) void k_cast_x(const float* __restrict__ x,
                                                u16* __restrict__ xA, int flip) {
  const int idx = blockIdx.x * 256 + threadIdx.x;  // [0, 4*2048*256)
  const int c = idx & 255;                         // f32x4 chunk within row
  const int l = (idx >> 8) & 2047;
  const int b = idx >> 19;
  const int ls = flip ? (2047 - l) : l;
  const f32x4 v = ((const f32x4*)x)[(long long)(b * 2048 + ls) * 256 + c];
  u16x4 o = {f2b(v[0]), f2b(v[1]), f2b(v[2]), f2b(v[3])};
  ((u16x4*)xA)[(long long)(b * 2048 + l) * 256 + c] = o;
}

__global__ __launch_bounds__(256) void k_prep_xw(const float* __restrict__ xpw,
                                                 u16* __restrict__ xw_pad) {
  const int idx = blockIdx.x * 256 + threadIdx.x;  // [0, 128*2048)
  const int c = idx & 2047;
  const int r = idx >> 11;
  xw_pad[idx] = (r < 96) ? f2b(xpw[r * 2048 + c]) : (u16)0;
}

__global__ __launch_bounds__(256) void k_prep_a2(const float* __restrict__ alog,
                                                 float* __restrict__ A2) {
  const int idx = blockIdx.x * 256 + threadIdx.x;  // [0, 2048*16)
  A2[idx] = -expf(alog[idx]) * 1.4426950408889634f;  // A * log2(e)
}

__global__ __launch_bounds__(256) void k_prep_bc(const u16* __restrict__ proj,
                                                 float* __restrict__ Bf,
                                                 float* __restrict__ Cf) {
  const int idx = blockIdx.x * 256 + threadIdx.x;  // [0, 8192*32)
  const int c = idx & 31;
  const long long gr = idx >> 5;
  const float v = b2f(proj[gr * 128 + 64 + c]);
  if (c < 16) Bf[gr * 16 + c] = v;
  else        Cf[gr * 16 + (c - 16)] = v;
}

// ---------------------------------------------------------------------------
// depthwise causal conv (k=4) + bias + silu.  xi lives in xz cols [0,2048).
// ---------------------------------------------------------------------------
__global__ __launch_bounds__(256) void k_conv(const u16* __restrict__ xz,
                                              const float* __restrict__ cw,
                                              const float* __restrict__ cb,
                                              u16* __restrict__ xc) {
  const int idx = blockIdx.x * 256 + threadIdx.x;  // [0, 8192*256)
  const int d8  = idx & 255;
  const int gr  = idx >> 8;
  const int t   = gr & 2047;
  const int d0  = d8 * 8;

  float acc[8];
#pragma unroll
  for (int j = 0; j < 8; ++j) acc[j] = cb[d0 + j];

#pragma unroll
  for (int k = 0; k < 4; ++k) {
    const int tt = t - 3 + k;
    if (tt < 0) continue;
    const u32x4 v = *(const u32x4*)(xz + (long long)(gr + k - 3) * 4096 + d0);
    const u16* pv = (const u16*)&v;
#pragma unroll
    for (int j = 0; j < 8; ++j)
      acc[j] = fmaf(cw[(d0 + j) * 4 + k], b2f(pv[j]), acc[j]);
  }
  u16 o[8];
#pragma unroll
  for (int j = 0; j < 8; ++j) {
    const float a = acc[j];
    o[j] = f2b(a / (1.f + expf(-a)));  // silu
  }
  *(u32x4*)(xc + (long long)gr * 2048 + d0) = *(const u32x4*)o;
}

// ---------------------------------------------------------------------------
// scan phase A: per-chunk local scan (h starts at 0). Writes y_local into the
// xi region of xz, plus chunk summaries h_loc[b][c][s][d] and sumdt[b][c][d].
// grid: 4(b) * 16(chunk) * 8(dchunk) = 512 blocks
// ---------------------------------------------------------------------------
__global__ __launch_bounds__(256) void k_scanA(
    const u16* __restrict__ dt, const u16* __restrict__ xc,
    const float* __restrict__ Bf, const float* __restrict__ Cf,
    const float* __restrict__ A2, u16* __restrict__ yz,
    float* __restrict__ h_loc, float* __restrict__ sumdt)
{
  const int tid = threadIdx.x;
  const int bx  = blockIdx.x;
  const int d     = (bx & 7) * 256 + tid;
  const int chunk = (bx >> 3) & 15;
  const int b     = bx >> 7;

  float a2[16];
#pragma unroll
  for (int s = 0; s < 16; ++s) a2[s] = A2[d * 16 + s];

  float h[16];
#pragma unroll
  for (int s = 0; s < 16; ++s) h[s] = 0.f;
  float sdt = 0.f;

  const long long rowBase = (long long)b * 2048 + chunk * 128;
  for (int t0 = 0; t0 < 128; ++t0) {
    const long long gr = rowBase + t0;
    const float dtv = b2f(dt[gr * 2048 + d]);
    const float xcv = b2f(xc[gr * 2048 + d]);
    sdt += dtv;
    const float dtx = dtv * xcv;
    float Bv[16], Cv[16];
    *(f32x4*)&Bv[0]  = *(const f32x4*)(Bf + gr * 16);
    *(f32x4*)&Bv[4]  = *(const f32x4*)(Bf + gr * 16 + 4);
    *(f32x4*)&Bv[8]  = *(const f32x4*)(Bf + gr * 16 + 8);
    *(f32x4*)&Bv[12] = *(const f32x4*)(Bf + gr * 16 + 12);
    *(f32x4*)&Cv[0]  = *(const f32x4*)(Cf + gr * 16);
    *(f32x4*)&Cv[4]  = *(const f32x4*)(Cf + gr * 16 + 4);
    *(f32x4*)&Cv[8]  = *(const f32x4*)(Cf + gr * 16 + 8);
    *(f32x4*)&Cv[12] = *(const f32x4*)(Cf + gr * 16 + 12);
    float y = 0.f;
#pragma unroll
    for (int s = 0; s < 16; ++s) {
      const float dA = __builtin_amdgcn_exp2f(a2[s] * dtv);
      h[s] = fmaf(h[s], dA, dtx * Bv[s]);
      y = fmaf(h[s], Cv[s], y);
    }
    yz[gr * 4096 + d] = f2b(y);
  }
  const long long cbi = (long long)b * 16 + chunk;
#pragma unroll
  for (int s = 0; s < 16; ++s) h_loc[(cbi * 16 + s) * 2048 + d] = h[s];
  sumdt[cbi * 2048 + d] = sdt;
}

// phase B: chain chunk states. h_in[c] = state entering chunk c. grid: 4*8=32
__global__ __launch_bounds__(256) void k_scanB(
    const float* __restrict__ A2, const float* __restrict__ h_loc,
    const float* __restrict__ sumdt, float* __restrict__ h_in)
{
  const int tid = threadIdx.x;
  const int bx  = blockIdx.x;
  const int d   = (bx & 7) * 256 + tid;
  const int b   = bx >> 3;

  float a2[16];
#pragma unroll
  for (int s = 0; s < 16; ++s) a2[s] = A2[d * 16 + s];
  float h[16];
#pragma unroll
  for (int s = 0; s < 16; ++s) h[s] = 0.f;

  const long long base = (long long)b * 16;
  for (int c = 0; c < 16; ++c) {
    const long long cbi = base + c;
#pragma unroll
    for (int s = 0; s < 16; ++s) h_in[(cbi * 16 + s) * 2048 + d] = h[s];
    const float sd = sumdt[cbi * 2048 + d];
#pragma unroll
    for (int s = 0; s < 16; ++s) {
      const float P = __builtin_amdgcn_exp2f(a2[s] * sd);
      h[s] = fmaf(h[s], P, h_loc[(cbi * 16 + s) * 2048 + d]);
    }
  }
}

// phase C: y_t += C_t . (exp2(a2 * cumdt_t) ⊙ h_in). chunks 1..15. grid 480
__global__ __launch_bounds__(256) void k_scanC(
    const u16* __restrict__ dt, const float* __restrict__ Cf,
    const float* __restrict__ A2, const float* __restrict__ h_in,
    u16* __restrict__ yz)
{
  const int tid = threadIdx.x;
  const int bx  = blockIdx.x;
  const int d   = (bx & 7) * 256 + tid;
  int r = bx >> 3;
  const int chunk = (r % 15) + 1;
  const int b = r / 15;

  float a2[16];
#pragma unroll
  for (int s = 0; s < 16; ++s) a2[s] = A2[d * 16 + s];
  const long long cbi = (long long)b * 16 + chunk;
  float hv[16];
#pragma unroll
  for (int s = 0; s < 16; ++s) hv[s] = h_in[(cbi * 16 + s) * 2048 + d];

  float cum = 0.f;
  const long long rowBase = (long long)b * 2048 + chunk * 128;
  for (int t0 = 0; t0 < 128; ++t0) {
    const long long gr = rowBase + t0;
    cum += b2f(dt[gr * 2048 + d]);
    float Cv[16];
    *(f32x4*)&Cv[0]  = *(const f32x4*)(Cf + gr * 16);
    *(f32x4*)&Cv[4]  = *(const f32x4*)(Cf + gr * 16 + 4);
    *(f32x4*)&Cv[8]  = *(const f32x4*)(Cf + gr * 16 + 8);
    *(f32x4*)&Cv[12] = *(const f32x4*)(Cf + gr * 16 + 12);
    float g = 0.f;
#pragma unroll
    for (int s = 0; s < 16; ++s) {
      const float w = __builtin_amdgcn_exp2f(a2[s] * cum);
      g = fmaf(w * hv[s], Cv[s], g);
    }
    u16* yp = &yz[gr * 4096 + d];
    *yp = f2b(b2f(*yp) + g);
  }
}

// gate: y = (y + xc*Dp) * silu(z), in place in xz cols [0,2048). grid 8192
__global__ __launch_bounds__(256) void k_gate(u16* __restrict__ xz,
                                              const u16* __restrict__ xc,
                                              const float* __restrict__ Dp) {
  const int idx = blockIdx.x * 256 + threadIdx.x;  // [0, 8192*256)
  const int d8  = idx & 255;
  const int gr  = idx >> 8;
  const int d0  = d8 * 8;

  u16* yp = xz + (long long)gr * 4096 + d0;
  const u32x4 yv = *(const u32x4*)yp;
  const u32x4 zv = *(const u32x4*)(xz + (long long)gr * 4096 + 2048 + d0);
  const u32x4 xv = *(const u32x4*)(xc + (long long)gr * 2048 + d0);
  const u16* ya = (const u16*)&yv;
  const u16* za = (const u16*)&zv;
  const u16* xa = (const u16*)&xv;
  u16 o[8];
#pragma unroll
  for (int j = 0; j < 8; ++j) {
    const float y = b2f(ya[j]) + b2f(xa[j]) * Dp[d0 + j];
    const float z = b2f(za[j]);
    o[j] = f2b(y * (z / (1.f + expf(-z))));
  }
  *(u32x4*)yp = *(const u32x4*)o;
}

// ---------------------------------------------------------------------------
extern "C" void kernel_launch(void* const* d_in, const int* in_sizes, int n_in,
                              void* d_out, int out_size, void* d_ws, size_t ws_size,
                              hipStream_t stream) {
  const float* x    = (const float*)d_in[0];
  const float* inw  = (const float*)d_in[1];
  const float* cw   = (const float*)d_in[2];
  const float* cb   = (const float*)d_in[3];
  const float* xpw  = (const float*)d_in[4];
  const float* dtw  = (const float*)d_in[5];
  const float* dtb  = (const float*)d_in[6];
  const float* alog = (const float*)d_in[7];
  const float* Dp   = (const float*)d_in[8];
  const float* ow   = (const float*)d_in[9];
  float* out = (float*)d_out;

  // workspace layout (bytes) — per-direction buffers reused across dir 0/1.
  char* ws = (char*)d_ws;
  float* outacc = (float*)(ws + 0);          //  33,554,432  [8192][1024] fp32
  u16*   xz_d   = (u16*)(ws + 33554432);     //  67,108,864  [8192][4096] xi|z -> y|z
  u16*   xc_d   = (u16*)(ws + 100663296);    //  33,554,432  [8192][2048]
  u16*   inwB   = (u16*)(ws + 100663296);    //   8,388,608  [4096][1024] (dead before conv)
  u16*   dt_d   = (u16*)(ws + 134217728);    //  33,554,432  [8192][2048]
  u16*   xA     = (u16*)(ws + 134217728);    //  16,777,216  [8192][1024] (dead before dt_proj)
  u16*   owB    = (u16*)(ws + 134217728);    //   4,194,304  [1024][2048] (after scanC/gate)
  u16*   proj_d = (u16*)(ws + 167772160);    //   2,097,152  [8192][128]
  u16*   xw_pad = (u16*)(ws + 169869312);    //     524,288  [128][2048]
  float* A2     = (float*)(ws + 170393600);  //     131,072  [2048][16]
  float* Bf     = (float*)(ws + 170524672);  //     524,288  [8192][16]
  float* Cf     = (float*)(ws + 171048960);  //     524,288
  float* h_loc  = (float*)(ws + 171573248);  //   8,388,608  [64][16][2048]
  float* h_in   = (float*)(ws + 179961856);  //   8,388,608
  float* sumdt  = (float*)(ws + 188350464);  //     524,288  [64][2048]
  u16*   dtwB   = (u16*)(ws + 188874752);    //     262,144  [2048][64]
  const size_t NEED = 189136896;

  (void)in_sizes; (void)n_in; (void)out_size;
  if (ws_size < NEED) {  // deterministic guard: leaves d_out zeroed -> clean fail
    fprintf(stderr, "[BiMamba] ws_size=%zu < needed %zu — aborting launch\n", ws_size, NEED);
    return;
  }

  for (int dir = 0; dir < 2; ++dir) {
    const float* inw_d = inw + (long long)dir * 4096 * 1024;
    const float* cw_d  = cw  + dir * 2048 * 4;
    const float* cb_d  = cb  + dir * 2048;
    const float* xpw_d = xpw + dir * 96 * 2048;
    const float* dtw_d = dtw + dir * 2048 * 64;
    const float* dtb_d = dtb + dir * 2048;
    const float* al_d  = alog + dir * 2048 * 16;
    const float* Dp_d  = Dp  + dir * 2048;
    const float* ow_d  = ow  + (long long)dir * 1024 * 2048;

    // casts & prep (xA in dt region; inwB in xc region — both dead later)
    k_cast_x<<<8192, 256, 0, stream>>>(x, xA, dir);
    k_castw<<<4096, 256, 0, stream>>>(inw_d, inwB);     // 4096*1024 /4 /256
    k_prep_xw<<<1024, 256, 0, stream>>>(xpw_d, xw_pad);
    k_castw<<<128, 256, 0, stream>>>(dtw_d, dtwB);      // 2048*64 /4 /256
    k_prep_a2<<<128, 256, 0, stream>>>(al_d, A2);

    // in_proj: xz = xA[8192,1024] x inwB[4096,1024]^T
    k_gemm<0><<<dim3(64, 32), 256, 0, stream>>>(
        xA, 1024, inwB, 1024, xz_d, 4096, 1024, nullptr, nullptr, nullptr);

    k_conv<<<8192, 256, 0, stream>>>(xz_d, cw_d, cb_d, xc_d);

    // x_proj: proj = xc[8192,2048] x xw_pad[128,2048]^T
    k_gemm<0><<<dim3(64, 1), 256, 0, stream>>>(
        xc_d, 2048, xw_pad, 2048, proj_d, 128, 2048, nullptr, nullptr, nullptr);

    k_prep_bc<<<1024, 256, 0, stream>>>(proj_d, Bf, Cf);

    // dt_proj: dt = softplus(proj[:, :64] x dtwB[2048,64]^T + dtb)
    k_gemm<1><<<dim3(64, 16), 256, 0, stream>>>(
        proj_d, 128, dtwB, 64, dt_d, 2048, 64, dtb_d, nullptr, nullptr);

    k_scanA<<<512, 256, 0, stream>>>(dt_d, xc_d, Bf, Cf, A2, xz_d, h_loc, sumdt);
    k_scanB<<<32, 256, 0, stream>>>(A2, h_loc, sumdt, h_in);
    k_scanC<<<480, 256, 0, stream>>>(dt_d, Cf, A2, h_in, xz_d);

    k_gate<<<8192, 256, 0, stream>>>(xz_d, xc_d, Dp_d);

    // out_proj weights -> bf16 (into dead dt region; dt unused after scanC)
    k_castw<<<2048, 256, 0, stream>>>(ow_d, owB);       // 1024*2048 /4 /256

    if (dir == 0) {
      // out_proj dir0 -> fp32 accumulator
      k_gemm<2><<<dim3(64, 8), 256, 0, stream>>>(
          xz_d, 4096, owB, 2048, outacc, 1024, 2048, nullptr, nullptr, nullptr);
    } else {
      // out_proj dir1: time-flip rows, add dir0, store fp32 to d_out
      k_gemm<3><<<dim3(64, 8), 256, 0, stream>>>(
          xz_d, 4096, owB, 2048, nullptr, 1024, 2048, nullptr, outacc, out);
    }
  }
}

// Round 6
// 1067.413 us; speedup vs baseline: 1.2005x; 1.1657x over previous
//
#include <hip/hip_runtime.h>
#include <hip/hip_bf16.h>
#include <math.h>
#include <stdio.h>

// BiMambaBlock: bidirectional Mamba forward.
// B=4, L=2048, D_MODEL=1024, D_INNER=2048, D_STATE=16, D_CONV=4, DT_RANK=64.
// Inputs/output fp32; GEMMs run bf16 MFMA (fp32 acc) via cast kernels.
//
// R5 -> R6: k_conv was #1 at 125 us with MfmaUtil 0 / VALU 13% / HBM 10% --
// address-divergence: cw[(d0+j)*4+k] gathers 64 distinct cache lines per
// load instr (32 gathers/thread ~= 262k TA-cycles/CU ~= the whole runtime).
// Fix: per-dir transpose cw -> cwT[4][2048] fp32 (k_prep_cw, 32 KB), conv
// reads become coalesced f32x4 loads. Everything else unchanged.
//
// Per direction (sequential, buffers reused; ws = 189.2 MB):
//   cast x(/flip) + weights -> GEMM in_proj -> conv+silu -> GEMM x_proj ->
//   split B/C -> GEMM dt_proj(+softplus) -> chunked scan (A/B/C) -> gate ->
//   cast ow -> GEMM out (dir0: fp32 acc; dir1: add + time-flip + store fp32).
// Scan chunking: prod exp(dt*A) telescopes = exp2(A*log2e * sum dt);
// 16 chunks of 128 steps -> parallel local scans + tiny chain + correction.

using u16 = unsigned short;
using u32 = unsigned int;

typedef __bf16 bf16x8 __attribute__((ext_vector_type(8)));
typedef float  f32x4  __attribute__((ext_vector_type(4)));
typedef u32    u32x4  __attribute__((ext_vector_type(4)));
typedef u16    u16x4  __attribute__((ext_vector_type(4)));

#define DEVINL __device__ __forceinline__

DEVINL float b2f(u16 u) { union { u32 i; float f; } v; v.i = ((u32)u) << 16; return v.f; }
DEVINL u16 f2b(float f) {
  union { float f; u32 i; } v; v.f = f;
  u32 i = v.i;
  return (u16)((i + 0x7FFFu + ((i >> 16) & 1u)) >> 16);  // RNE; inputs are tame (no NaN)
}

DEVINL void gl_lds16(const u16* g, u16* l) {
  __builtin_amdgcn_global_load_lds(
      (__attribute__((address_space(1))) void*)const_cast<u16*>(g),
      (__attribute__((address_space(3))) void*)l, 16, 0, 0);
}

// ---------------------------------------------------------------------------
// GEMM: C[m,n] = sum_k A[m,k] * B[n,k]   (both K-major, bf16 in, fp32 acc)
// 128x128 tile, BK=64, 256 threads (4 waves, each 64x64 = 4x4 mfma 16x16x32).
// MODE 0: store bf16       MODE 1: softplus(acc + bias[n]) -> bf16
// MODE 2: store fp32       MODE 3: fp32 store to out2 at row m^2047, += addsrc
// ---------------------------------------------------------------------------
template <int MODE>
__global__ __launch_bounds__(256) void k_gemm(
    const u16* __restrict__ A, int lda,
    const u16* __restrict__ Bw, int ldb,
    void* __restrict__ Cout, int ldc, int K,
    const float* __restrict__ bias,
    const float* __restrict__ addsrc, float* __restrict__ out2)
{
  __shared__ __align__(16) u16 As[128 * 64];
  __shared__ __align__(16) u16 Bs[128 * 64];

  const int tid  = threadIdx.x;
  const int lane = tid & 63;
  const int wid  = tid >> 6;

  const long long mBase = (long long)blockIdx.x * 128;
  const long long nBase = (long long)blockIdx.y * 128;

  f32x4 acc[4][4];
#pragma unroll
  for (int i = 0; i < 4; ++i)
#pragma unroll
    for (int j = 0; j < 4; ++j) acc[i][j] = (f32x4){0.f, 0.f, 0.f, 0.f};

  const int wm = (wid & 1) * 64;
  const int wn = (wid >> 1) * 64;
  const int lrow = lane & 15;
  const int lk   = (lane >> 4) * 8;
  const int sr = tid >> 3;         // staging row within 32-row group [0,32)
  const int sc = (tid & 7) * 8;    // staging col (8 bf16 = 16 B)

  for (int k0 = 0; k0 < K; k0 += 64) {
    // async staging: wave-uniform LDS base + HW lane*16B. Granule index
    // (i*32 + wid*8 + (lane>>3))*8 + (lane&7) == r*8 + c -> row-major [r][c].
#pragma unroll
    for (int i = 0; i < 4; ++i) {
      const int r = i * 32 + sr;
      u16* la = &As[(i * 256 + wid * 64) * 8];
      u16* lb = &Bs[(i * 256 + wid * 64) * 8];
      gl_lds16(A  + (mBase + r) * (long long)lda + (k0 + sc), la);
      gl_lds16(Bw + (nBase + r) * (long long)ldb + (k0 + sc), lb);
    }
    __syncthreads();  // drains vmcnt before s_barrier (compiler-inserted)
#pragma unroll
    for (int kk = 0; kk < 64; kk += 32) {
      bf16x8 af[4], bfr[4];
#pragma unroll
      for (int f = 0; f < 4; ++f) {
        af[f]  = *(const bf16x8*)&As[(wm + f * 16 + lrow) * 64 + kk + lk];
        bfr[f] = *(const bf16x8*)&Bs[(wn + f * 16 + lrow) * 64 + kk + lk];
      }
#pragma unroll
      for (int fm = 0; fm < 4; ++fm)
#pragma unroll
        for (int fn = 0; fn < 4; ++fn)
          acc[fm][fn] = __builtin_amdgcn_mfma_f32_16x16x32_bf16(af[fm], bfr[fn], acc[fm][fn], 0, 0, 0);
    }
    __syncthreads();
  }

  // epilogue: D lane mapping col = lane&15, row = (lane>>4)*4 + reg  [m89]
  const int rowq = (lane >> 4) * 4;
  const int coln = lane & 15;
#pragma unroll
  for (int fm = 0; fm < 4; ++fm) {
#pragma unroll
    for (int fn = 0; fn < 4; ++fn) {
#pragma unroll
      for (int r = 0; r < 4; ++r) {
        const long long m = mBase + wm + fm * 16 + rowq + r;
        const long long n = nBase + wn + fn * 16 + coln;
        const float v = acc[fm][fn][r];
        if constexpr (MODE == 0) {
          ((u16*)Cout)[m * ldc + n] = f2b(v);
        } else if constexpr (MODE == 1) {
          const float xv = v + bias[(int)n];
          const float sp = (xv > 20.f) ? xv : log1pf(expf(xv));
          ((u16*)Cout)[m * ldc + n] = f2b(sp);
        } else if constexpr (MODE == 2) {
          ((float*)Cout)[m * ldc + n] = v;
        } else {
          const long long mf = m ^ 2047;  // time flip within batch (L=2048)
          out2[mf * ldc + n] = v + addsrc[mf * ldc + n];
        }
      }
    }
  }
}

// ---------------------------------------------------------------------------
// cast / prep kernels (inputs fp32; weight pointers pre-offset per dir)
// ---------------------------------------------------------------------------
__global__ __launch_bounds__(256) void k_castw(const float* __restrict__ src,
                                               u16* __restrict__ dst) {
  const int i = blockIdx.x * 256 + threadIdx.x;  // one f32x4 chunk each
  const f32x4 v = ((const f32x4*)src)[i];
  u16x4 o = {f2b(v[0]), f2b(v[1]), f2b(v[2]), f2b(v[3])};
  ((u16x4*)dst)[i] = o;
}

// x (fp32 [4][2048][1024]) -> bf16, optional time flip per batch
__global__ __launch_bounds__(256) void k_cast_x(const float* __restrict__ x,
                                                u16* __restrict__ xA, int flip) {
  const int idx = blockIdx.x * 256 + threadIdx.x;  // [0, 4*2048*256)
  const int c = idx & 255;                         // f32x4 chunk within row
  const int l = (idx >> 8) & 2047;
  const int b = idx >> 19;
  const int ls = flip ? (2047 - l) : l;
  const f32x4 v = ((const f32x4*)x)[(long long)(b * 2048 + ls) * 256 + c];
  u16x4 o = {f2b(v[0]), f2b(v[1]), f2b(v[2]), f2b(v[3])};
  ((u16x4*)xA)[(long long)(b * 2048 + l) * 256 + c] = o;
}

__global__ __launch_bounds__(256) void k_prep_xw(const float* __restrict__ xpw,
                                                 u16* __restrict__ xw_pad) {
  const int idx = blockIdx.x * 256 + threadIdx.x;  // [0, 128*2048)
  const int c = idx & 2047;
  const int r = idx >> 11;
  xw_pad[idx] = (r < 96) ? f2b(xpw[r * 2048 + c]) : (u16)0;
}

__global__ __launch_bounds__(256) void k_prep_a2(const float* __restrict__ alog,
                                                 float* __restrict__ A2) {
  const int idx = blockIdx.x * 256 + threadIdx.x;  // [0, 2048*16)
  A2[idx] = -expf(alog[idx]) * 1.4426950408889634f;  // A * log2(e)
}

// cw [2048][4] -> cwT [4][2048] fp32 (kills the 128B-stride gather in conv)
__global__ __launch_bounds__(256) void k_prep_cw(const float* __restrict__ cw,
                                                 float* __restrict__ cwT) {
  const int idx = blockIdx.x * 256 + threadIdx.x;  // [0, 8192)
  const int d = idx & 2047;
  const int k = idx >> 11;
  cwT[k * 2048 + d] = cw[d * 4 + k];
}

__global__ __launch_bounds__(256) void k_prep_bc(const u16* __restrict__ proj,
                                                 float* __restrict__ Bf,
                                                 float* __restrict__ Cf) {
  const int idx = blockIdx.x * 256 + threadIdx.x;  // [0, 8192*32)
  const int c = idx & 31;
  const long long gr = idx >> 5;
  const float v = b2f(proj[gr * 128 + 64 + c]);
  if (c < 16) Bf[gr * 16 + c] = v;
  else        Cf[gr * 16 + (c - 16)] = v;
}

// ---------------------------------------------------------------------------
// depthwise causal conv (k=4) + bias + silu.  xi lives in xz cols [0,2048).
// cwT is [4][2048] so weight loads are coalesced f32x4.
// ---------------------------------------------------------------------------
__global__ __launch_bounds__(256) void k_conv(const u16* __restrict__ xz,
                                              const float* __restrict__ cwT,
                                              const float* __restrict__ cb,
                                              u16* __restrict__ xc) {
  const int idx = blockIdx.x * 256 + threadIdx.x;  // [0, 8192*256)
  const int d8  = idx & 255;
  const int gr  = idx >> 8;
  const int t   = gr & 2047;
  const int d0  = d8 * 8;

  float acc[8];
  {
    const f32x4 b0 = *(const f32x4*)(cb + d0);
    const f32x4 b1 = *(const f32x4*)(cb + d0 + 4);
#pragma unroll
    for (int j = 0; j < 4; ++j) { acc[j] = b0[j]; acc[4 + j] = b1[j]; }
  }

#pragma unroll
  for (int k = 0; k < 4; ++k) {
    const int tt = t - 3 + k;
    if (tt < 0) continue;
    const u32x4 v = *(const u32x4*)(xz + (long long)(gr + k - 3) * 4096 + d0);
    const u16* pv = (const u16*)&v;
    const f32x4 w0 = *(const f32x4*)(cwT + k * 2048 + d0);
    const f32x4 w1 = *(const f32x4*)(cwT + k * 2048 + d0 + 4);
#pragma unroll
    for (int j = 0; j < 4; ++j) {
      acc[j]     = fmaf(w0[j], b2f(pv[j]), acc[j]);
      acc[4 + j] = fmaf(w1[j], b2f(pv[4 + j]), acc[4 + j]);
    }
  }
  u16 o[8];
#pragma unroll
  for (int j = 0; j < 8; ++j) {
    const float a = acc[j];
    o[j] = f2b(a / (1.f + expf(-a)));  // silu
  }
  *(u32x4*)(xc + (long long)gr * 2048 + d0) = *(const u32x4*)o;
}

// ---------------------------------------------------------------------------
// scan phase A: per-chunk local scan (h starts at 0). Writes y_local into the
// xi region of xz, plus chunk summaries h_loc[b][c][s][d] and sumdt[b][c][d].
// grid: 4(b) * 16(chunk) * 8(dchunk) = 512 blocks
// ---------------------------------------------------------------------------
__global__ __launch_bounds__(256) void k_scanA(
    const u16* __restrict__ dt, const u16* __restrict__ xc,
    const float* __restrict__ Bf, const float* __restrict__ Cf,
    const float* __restrict__ A2, u16* __restrict__ yz,
    float* __restrict__ h_loc, float* __restrict__ sumdt)
{
  const int tid = threadIdx.x;
  const int bx  = blockIdx.x;
  const int d     = (bx & 7) * 256 + tid;
  const int chunk = (bx >> 3) & 15;
  const int b     = bx >> 7;

  float a2[16];
#pragma unroll
  for (int s = 0; s < 16; ++s) a2[s] = A2[d * 16 + s];

  float h[16];
#pragma unroll
  for (int s = 0; s < 16; ++s) h[s] = 0.f;
  float sdt = 0.f;

  const long long rowBase = (long long)b * 2048 + chunk * 128;
  for (int t0 = 0; t0 < 128; ++t0) {
    const long long gr = rowBase + t0;
    const float dtv = b2f(dt[gr * 2048 + d]);
    const float xcv = b2f(xc[gr * 2048 + d]);
    sdt += dtv;
    const float dtx = dtv * xcv;
    float Bv[16], Cv[16];
    *(f32x4*)&Bv[0]  = *(const f32x4*)(Bf + gr * 16);
    *(f32x4*)&Bv[4]  = *(const f32x4*)(Bf + gr * 16 + 4);
    *(f32x4*)&Bv[8]  = *(const f32x4*)(Bf + gr * 16 + 8);
    *(f32x4*)&Bv[12] = *(const f32x4*)(Bf + gr * 16 + 12);
    *(f32x4*)&Cv[0]  = *(const f32x4*)(Cf + gr * 16);
    *(f32x4*)&Cv[4]  = *(const f32x4*)(Cf + gr * 16 + 4);
    *(f32x4*)&Cv[8]  = *(const f32x4*)(Cf + gr * 16 + 8);
    *(f32x4*)&Cv[12] = *(const f32x4*)(Cf + gr * 16 + 12);
    float y = 0.f;
#pragma unroll
    for (int s = 0; s < 16; ++s) {
      const float dA = __builtin_amdgcn_exp2f(a2[s] * dtv);
      h[s] = fmaf(h[s], dA, dtx * Bv[s]);
      y = fmaf(h[s], Cv[s], y);
    }
    yz[gr * 4096 + d] = f2b(y);
  }
  const long long cbi = (long long)b * 16 + chunk;
#pragma unroll
  for (int s = 0; s < 16; ++s) h_loc[(cbi * 16 + s) * 2048 + d] = h[s];
  sumdt[cbi * 2048 + d] = sdt;
}

// phase B: chain chunk states. h_in[c] = state entering chunk c. grid: 4*8=32
__global__ __launch_bounds__(256) void k_scanB(
    const float* __restrict__ A2, const float* __restrict__ h_loc,
    const float* __restrict__ sumdt, float* __restrict__ h_in)
{
  const int tid = threadIdx.x;
  const int bx  = blockIdx.x;
  const int d   = (bx & 7) * 256 + tid;
  const int b   = bx >> 3;

  float a2[16];
#pragma unroll
  for (int s = 0; s < 16; ++s) a2[s] = A2[d * 16 + s];
  float h[16];
#pragma unroll
  for (int s = 0; s < 16; ++s) h[s] = 0.f;

  const long long base = (long long)b * 16;
  for (int c = 0; c < 16; ++c) {
    const long long cbi = base + c;
#pragma unroll
    for (int s = 0; s < 16; ++s) h_in[(cbi * 16 + s) * 2048 + d] = h[s];
    const float sd = sumdt[cbi * 2048 + d];
#pragma unroll
    for (int s = 0; s < 16; ++s) {
      const float P = __builtin_amdgcn_exp2f(a2[s] * sd);
      h[s] = fmaf(h[s], P, h_loc[(cbi * 16 + s) * 2048 + d]);
    }
  }
}

// phase C: y_t += C_t . (exp2(a2 * cumdt_t) ⊙ h_in). chunks 1..15. grid 480
__global__ __launch_bounds__(256) void k_scanC(
    const u16* __restrict__ dt, const float* __restrict__ Cf,
    const float* __restrict__ A2, const float* __restrict__ h_in,
    u16* __restrict__ yz)
{
  const int tid = threadIdx.x;
  const int bx  = blockIdx.x;
  const int d   = (bx & 7) * 256 + tid;
  int r = bx >> 3;
  const int chunk = (r % 15) + 1;
  const int b = r / 15;

  float a2[16];
#pragma unroll
  for (int s = 0; s < 16; ++s) a2[s] = A2[d * 16 + s];
  const long long cbi = (long long)b * 16 + chunk;
  float hv[16];
#pragma unroll
  for (int s = 0; s < 16; ++s) hv[s] = h_in[(cbi * 16 + s) * 2048 + d];

  float cum = 0.f;
  const long long rowBase = (long long)b * 2048 + chunk * 128;
  for (int t0 = 0; t0 < 128; ++t0) {
    const long long gr = rowBase + t0;
    cum += b2f(dt[gr * 2048 + d]);
    float Cv[16];
    *(f32x4*)&Cv[0]  = *(const f32x4*)(Cf + gr * 16);
    *(f32x4*)&Cv[4]  = *(const f32x4*)(Cf + gr * 16 + 4);
    *(f32x4*)&Cv[8]  = *(const f32x4*)(Cf + gr * 16 + 8);
    *(f32x4*)&Cv[12] = *(const f32x4*)(Cf + gr * 16 + 12);
    float g = 0.f;
#pragma unroll
    for (int s = 0; s < 16; ++s) {
      const float w = __builtin_amdgcn_exp2f(a2[s] * cum);
      g = fmaf(w * hv[s], Cv[s], g);
    }
    u16* yp = &yz[gr * 4096 + d];
    *yp = f2b(b2f(*yp) + g);
  }
}

// gate: y = (y + xc*Dp) * silu(z), in place in xz cols [0,2048). grid 8192
__global__ __launch_bounds__(256) void k_gate(u16* __restrict__ xz,
                                              const u16* __restrict__ xc,
                                              const float* __restrict__ Dp) {
  const int idx = blockIdx.x * 256 + threadIdx.x;  // [0, 8192*256)
  const int d8  = idx & 255;
  const int gr  = idx >> 8;
  const int d0  = d8 * 8;

  u16* yp = xz + (long long)gr * 4096 + d0;
  const u32x4 yv = *(const u32x4*)yp;
  const u32x4 zv = *(const u32x4*)(xz + (long long)gr * 4096 + 2048 + d0);
  const u32x4 xv = *(const u32x4*)(xc + (long long)gr * 2048 + d0);
  const u16* ya = (const u16*)&yv;
  const u16* za = (const u16*)&zv;
  const u16* xa = (const u16*)&xv;
  u16 o[8];
#pragma unroll
  for (int j = 0; j < 8; ++j) {
    const float y = b2f(ya[j]) + b2f(xa[j]) * Dp[d0 + j];
    const float z = b2f(za[j]);
    o[j] = f2b(y * (z / (1.f + expf(-z))));
  }
  *(u32x4*)yp = *(const u32x4*)o;
}

// ---------------------------------------------------------------------------
extern "C" void kernel_launch(void* const* d_in, const int* in_sizes, int n_in,
                              void* d_out, int out_size, void* d_ws, size_t ws_size,
                              hipStream_t stream) {
  const float* x    = (const float*)d_in[0];
  const float* inw  = (const float*)d_in[1];
  const float* cw   = (const float*)d_in[2];
  const float* cb   = (const float*)d_in[3];
  const float* xpw  = (const float*)d_in[4];
  const float* dtw  = (const float*)d_in[5];
  const float* dtb  = (const float*)d_in[6];
  const float* alog = (const float*)d_in[7];
  const float* Dp   = (const float*)d_in[8];
  const float* ow   = (const float*)d_in[9];
  float* out = (float*)d_out;

  // workspace layout (bytes) — per-direction buffers reused across dir 0/1.
  char* ws = (char*)d_ws;
  float* outacc = (float*)(ws + 0);          //  33,554,432  [8192][1024] fp32
  u16*   xz_d   = (u16*)(ws + 33554432);     //  67,108,864  [8192][4096] xi|z -> y|z
  u16*   xc_d   = (u16*)(ws + 100663296);    //  33,554,432  [8192][2048]
  u16*   inwB   = (u16*)(ws + 100663296);    //   8,388,608  [4096][1024] (dead before conv)
  u16*   dt_d   = (u16*)(ws + 134217728);    //  33,554,432  [8192][2048]
  u16*   xA     = (u16*)(ws + 134217728);    //  16,777,216  [8192][1024] (dead before dt_proj)
  u16*   owB    = (u16*)(ws + 134217728);    //   4,194,304  [1024][2048] (after scanC/gate)
  u16*   proj_d = (u16*)(ws + 167772160);    //   2,097,152  [8192][128]
  u16*   xw_pad = (u16*)(ws + 169869312);    //     524,288  [128][2048]
  float* A2     = (float*)(ws + 170393600);  //     131,072  [2048][16]
  float* Bf     = (float*)(ws + 170524672);  //     524,288  [8192][16]
  float* Cf     = (float*)(ws + 171048960);  //     524,288
  float* h_loc  = (float*)(ws + 171573248);  //   8,388,608  [64][16][2048]
  float* h_in   = (float*)(ws + 179961856);  //   8,388,608
  float* sumdt  = (float*)(ws + 188350464);  //     524,288  [64][2048]
  u16*   dtwB   = (u16*)(ws + 188874752);    //     262,144  [2048][64]
  float* cwT    = (float*)(ws + 189136896);  //      32,768  [4][2048]
  const size_t NEED = 189169664;

  (void)in_sizes; (void)n_in; (void)out_size;
  if (ws_size < NEED) {  // deterministic guard: leaves d_out zeroed -> clean fail
    fprintf(stderr, "[BiMamba] ws_size=%zu < needed %zu — aborting launch\n", ws_size, NEED);
    return;
  }

  for (int dir = 0; dir < 2; ++dir) {
    const float* inw_d = inw + (long long)dir * 4096 * 1024;
    const float* cw_d  = cw  + dir * 2048 * 4;
    const float* cb_d  = cb  + dir * 2048;
    const float* xpw_d = xpw + dir * 96 * 2048;
    const float* dtw_d = dtw + dir * 2048 * 64;
    const float* dtb_d = dtb + dir * 2048;
    const float* al_d  = alog + dir * 2048 * 16;
    const float* Dp_d  = Dp  + dir * 2048;
    const float* ow_d  = ow  + (long long)dir * 1024 * 2048;

    // casts & prep (xA in dt region; inwB in xc region — both dead later)
    k_cast_x<<<8192, 256, 0, stream>>>(x, xA, dir);
    k_castw<<<4096, 256, 0, stream>>>(inw_d, inwB);     // 4096*1024 /4 /256
    k_prep_xw<<<1024, 256, 0, stream>>>(xpw_d, xw_pad);
    k_castw<<<128, 256, 0, stream>>>(dtw_d, dtwB);      // 2048*64 /4 /256
    k_prep_a2<<<128, 256, 0, stream>>>(al_d, A2);
    k_prep_cw<<<32, 256, 0, stream>>>(cw_d, cwT);

    // in_proj: xz = xA[8192,1024] x inwB[4096,1024]^T
    k_gemm<0><<<dim3(64, 32), 256, 0, stream>>>(
        xA, 1024, inwB, 1024, xz_d, 4096, 1024, nullptr, nullptr, nullptr);

    k_conv<<<8192, 256, 0, stream>>>(xz_d, cwT, cb_d, xc_d);

    // x_proj: proj = xc[8192,2048] x xw_pad[128,2048]^T
    k_gemm<0><<<dim3(64, 1), 256, 0, stream>>>(
        xc_d, 2048, xw_pad, 2048, proj_d, 128, 2048, nullptr, nullptr, nullptr);

    k_prep_bc<<<1024, 256, 0, stream>>>(proj_d, Bf, Cf);

    // dt_proj: dt = softplus(proj[:, :64] x dtwB[2048,64]^T + dtb)
    k_gemm<1><<<dim3(64, 16), 256, 0, stream>>>(
        proj_d, 128, dtwB, 64, dt_d, 2048, 64, dtb_d, nullptr, nullptr);

    k_scanA<<<512, 256, 0, stream>>>(dt_d, xc_d, Bf, Cf, A2, xz_d, h_loc, sumdt);
    k_scanB<<<32, 256, 0, stream>>>(A2, h_loc, sumdt, h_in);
    k_scanC<<<480, 256, 0, stream>>>(dt_d, Cf, A2, h_in, xz_d);

    k_gate<<<8192, 256, 0, stream>>>(xz_d, xc_d, Dp_d);

    // out_proj weights -> bf16 (into dead dt region; dt unused after scanC)
    k_castw<<<2048, 256, 0, stream>>>(ow_d, owB);       // 1024*2048 /4 /256

    if (dir == 0) {
      // out_proj dir0 -> fp32 accumulator
      k_gemm<2><<<dim3(64, 8), 256, 0, stream>>>(
          xz_d, 4096, owB, 2048, outacc, 1024, 2048, nullptr, nullptr, nullptr);
    } else {
      // out_proj dir1: time-flip rows, add dir0, store fp32 to d_out
      k_gemm<3><<<dim3(64, 8), 256, 0, stream>>>(
          xz_d, 4096, owB, 2048, nullptr, 1024, 2048, nullptr, outacc, out);
    }
  }
}

// Round 7
// 1019.839 us; speedup vs baseline: 1.2565x; 1.0466x over previous
//
#include <hip/hip_runtime.h>
#include <hip/hip_bf16.h>
#include <math.h>
#include <stdio.h>

// BiMambaBlock: bidirectional Mamba forward.
// B=4, L=2048, D_MODEL=1024, D_INNER=2048, D_STATE=16, D_CONV=4, DT_RANK=64.
// Inputs/output fp32; GEMMs run bf16 MFMA (fp32 acc) via cast kernels.
//
// R6 -> R7: dispatch-count attack (34 -> 21) + traffic fusions:
//  1. dir1 time-flip moved into GEMM A-staging (row ^= 2047, SGPR select);
//     cast_x runs once, xA persistent.
//  2. 5 per-dir prep/cast kernels fused into one block-range kernel.
//  3. x_proj epilogue (MODE 4) writes Bf/Cf fp32 directly; prep_bc dropped;
//     proj stride 128 -> 64 (cols >=64 never stored).
//  4. gate fused into scanC (k_scanCG, all 16 chunks; chunk0 = gate only)
//     -- saves a 64 MB/dir y round-trip and is slightly MORE precise.
// k_gemm inner loop unchanged (in_proj structural tile change staged next).
//
// Per direction: prep -> GEMM in_proj(flipA=dir) -> conv+silu -> GEMM x_proj
// (MODE4) -> GEMM dt_proj(+softplus) -> scanA/B/CG -> cast ow -> GEMM out.
// Scan chunking: prod exp(dt*A) telescopes = exp2(A*log2e * sum dt).

using u16 = unsigned short;
using u32 = unsigned int;

typedef __bf16 bf16x8 __attribute__((ext_vector_type(8)));
typedef float  f32x4  __attribute__((ext_vector_type(4)));
typedef u32    u32x4  __attribute__((ext_vector_type(4)));
typedef u16    u16x4  __attribute__((ext_vector_type(4)));

#define DEVINL __device__ __forceinline__

DEVINL float b2f(u16 u) { union { u32 i; float f; } v; v.i = ((u32)u) << 16; return v.f; }
DEVINL u16 f2b(float f) {
  union { float f; u32 i; } v; v.f = f;
  u32 i = v.i;
  return (u16)((i + 0x7FFFu + ((i >> 16) & 1u)) >> 16);  // RNE; inputs are tame (no NaN)
}

DEVINL void gl_lds16(const u16* g, u16* l) {
  __builtin_amdgcn_global_load_lds(
      (__attribute__((address_space(1))) void*)const_cast<u16*>(g),
      (__attribute__((address_space(3))) void*)l, 16, 0, 0);
}

// ---------------------------------------------------------------------------
// GEMM: C[m,n] = sum_k A[m,k] * B[n,k]   (both K-major, bf16 in, fp32 acc)
// 128x128 tile, BK=64, 256 threads (4 waves, each 64x64 = 4x4 mfma 16x16x32).
// flipA: A-row index ^= 2047 (batch-local time reversal, L=2048).
// MODE 0: store bf16                MODE 1: softplus(acc + f1[n]) -> bf16
// MODE 2: store fp32                MODE 3: fp32 store to out2 at m^2047, += f2
// MODE 4: n<64 -> bf16 Cout; n in [64,96) -> split fp32 to f1(B)/f2(C)
// ---------------------------------------------------------------------------
template <int MODE>
__global__ __launch_bounds__(256) void k_gemm(
    const u16* __restrict__ A, int lda, int flipA,
    const u16* __restrict__ Bw, int ldb,
    void* __restrict__ Cout, int ldc, int K,
    float* __restrict__ f1, float* __restrict__ f2,
    float* __restrict__ out2)
{
  __shared__ __align__(16) u16 As[128 * 64];
  __shared__ __align__(16) u16 Bs[128 * 64];

  const int tid  = threadIdx.x;
  const int lane = tid & 63;
  const int wid  = tid >> 6;

  const int mBase = blockIdx.x * 128;
  const int nBase = blockIdx.y * 128;

  f32x4 acc[4][4];
#pragma unroll
  for (int i = 0; i < 4; ++i)
#pragma unroll
    for (int j = 0; j < 4; ++j) acc[i][j] = (f32x4){0.f, 0.f, 0.f, 0.f};

  const int wm = (wid & 1) * 64;
  const int wn = (wid >> 1) * 64;
  const int lrow = lane & 15;
  const int lk   = (lane >> 4) * 8;
  const int sr = tid >> 3;         // staging row within 32-row group [0,32)
  const int sc = (tid & 7) * 8;    // staging col (8 bf16 = 16 B)

  for (int k0 = 0; k0 < K; k0 += 64) {
    // async staging: wave-uniform LDS base + HW lane*16B. Granule index
    // (i*32 + wid*8 + (lane>>3))*8 + (lane&7) == r*8 + c -> row-major [r][c].
#pragma unroll
    for (int i = 0; i < 4; ++i) {
      int ra = mBase + i * 32 + sr;
      if (flipA) ra ^= 2047;               // SGPR-uniform time flip
      const int rb = nBase + i * 32 + sr;
      u16* la = &As[(i * 256 + wid * 64) * 8];
      u16* lb = &Bs[(i * 256 + wid * 64) * 8];
      gl_lds16(A  + (long long)ra * lda + (k0 + sc), la);
      gl_lds16(Bw + (long long)rb * ldb + (k0 + sc), lb);
    }
    __syncthreads();  // drains vmcnt before s_barrier (compiler-inserted)
#pragma unroll
    for (int kk = 0; kk < 64; kk += 32) {
      bf16x8 af[4], bfr[4];
#pragma unroll
      for (int f = 0; f < 4; ++f) {
        af[f]  = *(const bf16x8*)&As[(wm + f * 16 + lrow) * 64 + kk + lk];
        bfr[f] = *(const bf16x8*)&Bs[(wn + f * 16 + lrow) * 64 + kk + lk];
      }
#pragma unroll
      for (int fm = 0; fm < 4; ++fm)
#pragma unroll
        for (int fn = 0; fn < 4; ++fn)
          acc[fm][fn] = __builtin_amdgcn_mfma_f32_16x16x32_bf16(af[fm], bfr[fn], acc[fm][fn], 0, 0, 0);
    }
    __syncthreads();
  }

  // epilogue: D lane mapping col = lane&15, row = (lane>>4)*4 + reg  [m89]
  const int rowq = (lane >> 4) * 4;
  const int coln = lane & 15;
#pragma unroll
  for (int fm = 0; fm < 4; ++fm) {
#pragma unroll
    for (int fn = 0; fn < 4; ++fn) {
#pragma unroll
      for (int r = 0; r < 4; ++r) {
        const long long m = mBase + wm + fm * 16 + rowq + r;
        const long long n = nBase + wn + fn * 16 + coln;
        const float v = acc[fm][fn][r];
        if constexpr (MODE == 0) {
          ((u16*)Cout)[m * ldc + n] = f2b(v);
        } else if constexpr (MODE == 1) {
          const float xv = v + f1[(int)n];
          const float sp = (xv > 20.f) ? xv : log1pf(expf(xv));
          ((u16*)Cout)[m * ldc + n] = f2b(sp);
        } else if constexpr (MODE == 2) {
          ((float*)Cout)[m * ldc + n] = v;
        } else if constexpr (MODE == 3) {
          const long long mf = m ^ 2047;  // time flip within batch (L=2048)
          out2[mf * ldc + n] = v + f2[mf * ldc + n];
        } else {  // MODE 4 (x_proj): dt-raw -> proj bf16; B/C -> fp32 split
          if (n < 64)       ((u16*)Cout)[m * ldc + n] = f2b(v);
          else if (n < 80)  f1[m * 16 + (n - 64)] = v;
          else if (n < 96)  f2[m * 16 + (n - 80)] = v;
          // n in [96,128): padding, dropped
        }
      }
    }
  }
}

// ---------------------------------------------------------------------------
// fused per-dir prep: [0,4096) castw inw | [4096,5120) pad+cast xw |
// [5120,5248) castw dtw | [5248,5376) A2 | [5376,5408) cwT transpose
// ---------------------------------------------------------------------------
__global__ __launch_bounds__(256) void k_prep(
    const float* __restrict__ inw_d, u16* __restrict__ inwB,
    const float* __restrict__ xpw_d, u16* __restrict__ xw_pad,
    const float* __restrict__ dtw_d, u16* __restrict__ dtwB,
    const float* __restrict__ alog_d, float* __restrict__ A2,
    const float* __restrict__ cw_d, float* __restrict__ cwT)
{
  const int bx = blockIdx.x;
  const int tid = threadIdx.x;
  if (bx < 4096) {
    const int i = bx * 256 + tid;
    const f32x4 v = ((const f32x4*)inw_d)[i];
    u16x4 o = {f2b(v[0]), f2b(v[1]), f2b(v[2]), f2b(v[3])};
    ((u16x4*)inwB)[i] = o;
  } else if (bx < 5120) {
    const int idx = (bx - 4096) * 256 + tid;  // [0, 128*2048)
    const int c = idx & 2047, r = idx >> 11;
    xw_pad[idx] = (r < 96) ? f2b(xpw_d[r * 2048 + c]) : (u16)0;
  } else if (bx < 5248) {
    const int i = (bx - 5120) * 256 + tid;    // 2048*64/4
    const f32x4 v = ((const f32x4*)dtw_d)[i];
    u16x4 o = {f2b(v[0]), f2b(v[1]), f2b(v[2]), f2b(v[3])};
    ((u16x4*)dtwB)[i] = o;
  } else if (bx < 5376) {
    const int idx = (bx - 5248) * 256 + tid;  // [0, 2048*16)
    A2[idx] = -expf(alog_d[idx]) * 1.4426950408889634f;  // A * log2(e)
  } else {
    const int idx = (bx - 5376) * 256 + tid;  // [0, 8192)
    const int d = idx & 2047, k = idx >> 11;
    cwT[k * 2048 + d] = cw_d[d * 4 + k];      // [2048][4] -> [4][2048]
  }
}

__global__ __launch_bounds__(256) void k_castw(const float* __restrict__ src,
                                               u16* __restrict__ dst) {
  const int i = blockIdx.x * 256 + threadIdx.x;
  const f32x4 v = ((const f32x4*)src)[i];
  u16x4 o = {f2b(v[0]), f2b(v[1]), f2b(v[2]), f2b(v[3])};
  ((u16x4*)dst)[i] = o;
}

// x fp32 [4][2048][1024] -> bf16 (no flip; dir1 flip happens in GEMM staging)
__global__ __launch_bounds__(256) void k_cast_x(const float* __restrict__ x,
                                                u16* __restrict__ xA) {
  const int idx = blockIdx.x * 256 + threadIdx.x;  // [0, 4*2048*256)
  const f32x4 v = ((const f32x4*)x)[idx];
  u16x4 o = {f2b(v[0]), f2b(v[1]), f2b(v[2]), f2b(v[3])};
  ((u16x4*)xA)[idx] = o;
}

// ---------------------------------------------------------------------------
// depthwise causal conv (k=4) + bias + silu.  xi lives in xz cols [0,2048).
// ---------------------------------------------------------------------------
__global__ __launch_bounds__(256) void k_conv(const u16* __restrict__ xz,
                                              const float* __restrict__ cwT,
                                              const float* __restrict__ cb,
                                              u16* __restrict__ xc) {
  const int idx = blockIdx.x * 256 + threadIdx.x;  // [0, 8192*256)
  const int d8  = idx & 255;
  const int gr  = idx >> 8;
  const int t   = gr & 2047;
  const int d0  = d8 * 8;

  float acc[8];
  {
    const f32x4 b0 = *(const f32x4*)(cb + d0);
    const f32x4 b1 = *(const f32x4*)(cb + d0 + 4);
#pragma unroll
    for (int j = 0; j < 4; ++j) { acc[j] = b0[j]; acc[4 + j] = b1[j]; }
  }

#pragma unroll
  for (int k = 0; k < 4; ++k) {
    const int tt = t - 3 + k;
    if (tt < 0) continue;
    const u32x4 v = *(const u32x4*)(xz + (long long)(gr + k - 3) * 4096 + d0);
    const u16* pv = (const u16*)&v;
    const f32x4 w0 = *(const f32x4*)(cwT + k * 2048 + d0);
    const f32x4 w1 = *(const f32x4*)(cwT + k * 2048 + d0 + 4);
#pragma unroll
    for (int j = 0; j < 4; ++j) {
      acc[j]     = fmaf(w0[j], b2f(pv[j]), acc[j]);
      acc[4 + j] = fmaf(w1[j], b2f(pv[4 + j]), acc[4 + j]);
    }
  }
  u16 o[8];
#pragma unroll
  for (int j = 0; j < 8; ++j) {
    const float a = acc[j];
    o[j] = f2b(a / (1.f + expf(-a)));  // silu
  }
  *(u32x4*)(xc + (long long)gr * 2048 + d0) = *(const u32x4*)o;
}

// ---------------------------------------------------------------------------
// scan phase A: per-chunk local scan (h starts at 0). Writes y_local into the
// xi region of xz, plus chunk summaries h_loc[b][c][s][d] and sumdt[b][c][d].
// grid: 4(b) * 16(chunk) * 8(dchunk) = 512 blocks
// ---------------------------------------------------------------------------
__global__ __launch_bounds__(256) void k_scanA(
    const u16* __restrict__ dt, const u16* __restrict__ xc,
    const float* __restrict__ Bf, const float* __restrict__ Cf,
    const float* __restrict__ A2, u16* __restrict__ yz,
    float* __restrict__ h_loc, float* __restrict__ sumdt)
{
  const int tid = threadIdx.x;
  const int bx  = blockIdx.x;
  const int d     = (bx & 7) * 256 + tid;
  const int chunk = (bx >> 3) & 15;
  const int b     = bx >> 7;

  float a2[16];
#pragma unroll
  for (int s = 0; s < 16; ++s) a2[s] = A2[d * 16 + s];

  float h[16];
#pragma unroll
  for (int s = 0; s < 16; ++s) h[s] = 0.f;
  float sdt = 0.f;

  const long long rowBase = (long long)b * 2048 + chunk * 128;
  for (int t0 = 0; t0 < 128; ++t0) {
    const long long gr = rowBase + t0;
    const float dtv = b2f(dt[gr * 2048 + d]);
    const float xcv = b2f(xc[gr * 2048 + d]);
    sdt += dtv;
    const float dtx = dtv * xcv;
    float Bv[16], Cv[16];
    *(f32x4*)&Bv[0]  = *(const f32x4*)(Bf + gr * 16);
    *(f32x4*)&Bv[4]  = *(const f32x4*)(Bf + gr * 16 + 4);
    *(f32x4*)&Bv[8]  = *(const f32x4*)(Bf + gr * 16 + 8);
    *(f32x4*)&Bv[12] = *(const f32x4*)(Bf + gr * 16 + 12);
    *(f32x4*)&Cv[0]  = *(const f32x4*)(Cf + gr * 16);
    *(f32x4*)&Cv[4]  = *(const f32x4*)(Cf + gr * 16 + 4);
    *(f32x4*)&Cv[8]  = *(const f32x4*)(Cf + gr * 16 + 8);
    *(f32x4*)&Cv[12] = *(const f32x4*)(Cf + gr * 16 + 12);
    float y = 0.f;
#pragma unroll
    for (int s = 0; s < 16; ++s) {
      const float dA = __builtin_amdgcn_exp2f(a2[s] * dtv);
      h[s] = fmaf(h[s], dA, dtx * Bv[s]);
      y = fmaf(h[s], Cv[s], y);
    }
    yz[gr * 4096 + d] = f2b(y);
  }
  const long long cbi = (long long)b * 16 + chunk;
#pragma unroll
  for (int s = 0; s < 16; ++s) h_loc[(cbi * 16 + s) * 2048 + d] = h[s];
  sumdt[cbi * 2048 + d] = sdt;
}

// phase B: chain chunk states. h_in[c] = state entering chunk c. grid: 4*8=32
__global__ __launch_bounds__(256) void k_scanB(
    const float* __restrict__ A2, const float* __restrict__ h_loc,
    const float* __restrict__ sumdt, float* __restrict__ h_in)
{
  const int tid = threadIdx.x;
  const int bx  = blockIdx.x;
  const int d   = (bx & 7) * 256 + tid;
  const int b   = bx >> 3;

  float a2[16];
#pragma unroll
  for (int s = 0; s < 16; ++s) a2[s] = A2[d * 16 + s];
  float h[16];
#pragma unroll
  for (int s = 0; s < 16; ++s) h[s] = 0.f;

  const long long base = (long long)b * 16;
  for (int c = 0; c < 16; ++c) {
    const long long cbi = base + c;
#pragma unroll
    for (int s = 0; s < 16; ++s) h_in[(cbi * 16 + s) * 2048 + d] = h[s];
    const float sd = sumdt[cbi * 2048 + d];
#pragma unroll
    for (int s = 0; s < 16; ++s) {
      const float P = __builtin_amdgcn_exp2f(a2[s] * sd);
      h[s] = fmaf(h[s], P, h_loc[(cbi * 16 + s) * 2048 + d]);
    }
  }
}

// ---------------------------------------------------------------------------
// phase C + gate fused. chunks 0..15 (chunk 0: gate only, block-uniform).
// y_fin = (y + corr + xc*Dp) * silu(z), written in place. grid 512.
// ---------------------------------------------------------------------------
__global__ __launch_bounds__(256) void k_scanCG(
    const u16* __restrict__ dt, const u16* __restrict__ xc,
    const float* __restrict__ Cf, const float* __restrict__ A2,
    const float* __restrict__ h_in, const float* __restrict__ Dp,
    u16* __restrict__ yz)
{
  const int tid = threadIdx.x;
  const int bx  = blockIdx.x;
  const int d     = (bx & 7) * 256 + tid;
  const int chunk = (bx >> 3) & 15;
  const int b     = bx >> 7;
  const float dp  = Dp[d];
  const long long rowBase = (long long)b * 2048 + chunk * 128;

  if (chunk == 0) {  // no cross-chunk correction for the first chunk
    for (int t0 = 0; t0 < 128; ++t0) {
      const long long gr = rowBase + t0;
      u16* yp = &yz[gr * 4096 + d];
      const float y = b2f(*yp) + b2f(xc[gr * 2048 + d]) * dp;
      const float z = b2f(yz[gr * 4096 + 2048 + d]);
      *yp = f2b(y * (z / (1.f + expf(-z))));
    }
    return;
  }

  float a2[16];
#pragma unroll
  for (int s = 0; s < 16; ++s) a2[s] = A2[d * 16 + s];
  const long long cbi = (long long)b * 16 + chunk;
  float hv[16];
#pragma unroll
  for (int s = 0; s < 16; ++s) hv[s] = h_in[(cbi * 16 + s) * 2048 + d];

  float cum = 0.f;
  for (int t0 = 0; t0 < 128; ++t0) {
    const long long gr = rowBase + t0;
    cum += b2f(dt[gr * 2048 + d]);
    float Cv[16];
    *(f32x4*)&Cv[0]  = *(const f32x4*)(Cf + gr * 16);
    *(f32x4*)&Cv[4]  = *(const f32x4*)(Cf + gr * 16 + 4);
    *(f32x4*)&Cv[8]  = *(const f32x4*)(Cf + gr * 16 + 8);
    *(f32x4*)&Cv[12] = *(const f32x4*)(Cf + gr * 16 + 12);
    float g = 0.f;
#pragma unroll
    for (int s = 0; s < 16; ++s) {
      const float w = __builtin_amdgcn_exp2f(a2[s] * cum);
      g = fmaf(w * hv[s], Cv[s], g);
    }
    u16* yp = &yz[gr * 4096 + d];
    const float y = b2f(*yp) + g + b2f(xc[gr * 2048 + d]) * dp;
    const float z = b2f(yz[gr * 4096 + 2048 + d]);
    *yp = f2b(y * (z / (1.f + expf(-z))));
  }
}

// ---------------------------------------------------------------------------
extern "C" void kernel_launch(void* const* d_in, const int* in_sizes, int n_in,
                              void* d_out, int out_size, void* d_ws, size_t ws_size,
                              hipStream_t stream) {
  const float* x    = (const float*)d_in[0];
  const float* inw  = (const float*)d_in[1];
  const float* cw   = (const float*)d_in[2];
  const float* cb   = (const float*)d_in[3];
  const float* xpw  = (const float*)d_in[4];
  const float* dtw  = (const float*)d_in[5];
  const float* dtb  = (const float*)d_in[6];
  const float* alog = (const float*)d_in[7];
  const float* Dp   = (const float*)d_in[8];
  const float* ow   = (const float*)d_in[9];
  float* out = (float*)d_out;

  // workspace layout (bytes) — per-direction buffers reused across dir 0/1.
  char* ws = (char*)d_ws;
  float* outacc = (float*)(ws + 0);          //  33,554,432  [8192][1024] fp32
  u16*   xz_d   = (u16*)(ws + 33554432);     //  67,108,864  [8192][4096] xi|z -> y|z
  u16*   xc_d   = (u16*)(ws + 100663296);    //  33,554,432  [8192][2048]
  u16*   inwB   = (u16*)(ws + 100663296);    //   8,388,608  (xc dead during in_proj)
  u16*   dt_d   = (u16*)(ws + 134217728);    //  33,554,432  [8192][2048]
  u16*   owB    = (u16*)(ws + 134217728);    //   4,194,304  (dt dead after scanCG)
  u16*   xA     = (u16*)(ws + 167772160);    //  16,777,216  [8192][1024] persistent
  u16*   proj_d = (u16*)(ws + 184549376);    //   1,048,576  [8192][64] (stride 64)
  u16*   xw_pad = (u16*)(ws + 185597952);    //     524,288  [128][2048]
  float* A2     = (float*)(ws + 186122240);  //     131,072  [2048][16]
  float* Bf     = (float*)(ws + 186253312);  //     524,288  [8192][16]
  float* Cf     = (float*)(ws + 186777600);  //     524,288
  float* h_loc  = (float*)(ws + 187301888);  //   8,388,608  [64][16][2048]
  float* h_in   = (float*)(ws + 195690496);  //   8,388,608
  float* sumdt  = (float*)(ws + 204079104);  //     524,288  [64][2048]
  u16*   dtwB   = (u16*)(ws + 204603392);    //     262,144  [2048][64]
  float* cwT    = (float*)(ws + 204865536);  //      32,768  [4][2048]
  const size_t NEED = 204898304;  // <= 205,651,968 proven available (R2 ran)

  (void)in_sizes; (void)n_in; (void)out_size;
  if (ws_size < NEED) {  // deterministic guard: leaves d_out zeroed -> clean fail
    fprintf(stderr, "[BiMamba] ws_size=%zu < needed %zu — aborting launch\n", ws_size, NEED);
    return;
  }

  k_cast_x<<<8192, 256, 0, stream>>>(x, xA);  // once; dir1 flips in staging

  for (int dir = 0; dir < 2; ++dir) {
    const float* inw_d = inw + (long long)dir * 4096 * 1024;
    const float* cw_d  = cw  + dir * 2048 * 4;
    const float* cb_d  = cb  + dir * 2048;
    const float* xpw_d = xpw + dir * 96 * 2048;
    const float* dtw_d = dtw + dir * 2048 * 64;
    const float* dtb_d = dtb + dir * 2048;
    const float* al_d  = alog + dir * 2048 * 16;
    const float* Dp_d  = Dp  + dir * 2048;
    const float* ow_d  = ow  + (long long)dir * 1024 * 2048;

    k_prep<<<5408, 256, 0, stream>>>(inw_d, inwB, xpw_d, xw_pad,
                                     dtw_d, dtwB, al_d, A2, cw_d, cwT);

    // in_proj: xz = xA[8192,1024] x inwB[4096,1024]^T  (dir1: A rows ^2047)
    k_gemm<0><<<dim3(64, 32), 256, 0, stream>>>(
        xA, 1024, dir, inwB, 1024, xz_d, 4096, 1024, nullptr, nullptr, nullptr);

    k_conv<<<8192, 256, 0, stream>>>(xz_d, cwT, cb_d, xc_d);

    // x_proj: proj(dt-raw, stride 64) + Bf/Cf fp32 split, fused epilogue
    k_gemm<4><<<dim3(64, 1), 256, 0, stream>>>(
        xc_d, 2048, 0, xw_pad, 2048, proj_d, 64, 2048, Bf, Cf, nullptr);

    // dt_proj: dt = softplus(proj[8192,64] x dtwB[2048,64]^T + dtb)
    k_gemm<1><<<dim3(64, 16), 256, 0, stream>>>(
        proj_d, 64, 0, dtwB, 64, dt_d, 2048, 64,
        const_cast<float*>(dtb_d), nullptr, nullptr);

    k_scanA<<<512, 256, 0, stream>>>(dt_d, xc_d, Bf, Cf, A2, xz_d, h_loc, sumdt);
    k_scanB<<<32, 256, 0, stream>>>(A2, h_loc, sumdt, h_in);
    k_scanCG<<<512, 256, 0, stream>>>(dt_d, xc_d, Cf, A2, h_in, Dp_d, xz_d);

    // out_proj weights -> bf16 (dt region dead after scanCG)
    k_castw<<<2048, 256, 0, stream>>>(ow_d, owB);

    if (dir == 0) {
      k_gemm<2><<<dim3(64, 8), 256, 0, stream>>>(
          xz_d, 4096, 0, owB, 2048, outacc, 1024, 2048, nullptr, nullptr, nullptr);
    } else {
      k_gemm<3><<<dim3(64, 8), 256, 0, stream>>>(
          xz_d, 4096, 0, owB, 2048, nullptr, 1024, 2048,
          nullptr, outacc, out);
    }
  }
}